// Round 3
// baseline (175.938 us; speedup 1.0000x reference)
//
#include <hip/hip_runtime.h>

#define B_SZ 8
#define L_SEQ 144
#define NTOK 1152
#define D_MODEL 256
#define D_INNER 512
#define D_STATE 64
#define DT_RANK 4
#define NDBC 132
#define SLAB 152064   // NTOK*NDBC, one split-K slab of dBC

#define BM 64
#define BN 64
#define BK 16
#define BN3 16        // gemm3 N-tile

// ---------------------------------------------------------------------------
// Tiled GEMM with register prefetch of the next k-slab.
//  A_MK=true : A stored [m][k] (row stride lda) | false: A stored [k][m]
//  B always stored [n][k] (row stride ldb)
//  GN        : guard n<N on B-loads and C-stores (N=132 case)
//  CONV      : (A_MK=false only) A rows are pre-conv xzT[d][tok]; apply
//              depthwise conv(4)+SiLU on the fly while staging to LDS.
// Split-K: blockIdx.z selects k-slab; C advanced by z*sstride.
// ---------------------------------------------------------------------------
template<bool A_MK, bool GN, bool CONV>
__global__ __launch_bounds__(256) void gemm_k(const float* __restrict__ A,
                                              const float* __restrict__ Bm,
                                              float* __restrict__ C,
                                              const int N, const int lda, const int ldb,
                                              const int ldc,
                                              const float* __restrict__ cw,
                                              const float* __restrict__ cb,
                                              const int kslab, const size_t sstride) {
    __shared__ float As[BK][BM + 4];
    __shared__ float Bs[BK][BN + 4];
    const int tid = threadIdx.x;
    const int m0 = blockIdx.y * BM;
    const int n0 = blockIdx.x * BN;
    const int kbeg = blockIdx.z * kslab;
    const int kend = kbeg + kslab;
    const int ty = tid >> 4, tx = tid & 15;
    const int lrow = tid >> 2, kq = (tid & 3) * 4;   // transpose-load indices
    const int kk = tid >> 4, cc = (tid & 15) * 4;    // direct-load indices
    float acc[4][4] = {};
    float4 av, bv, cw4;
    float xm2 = 0.f, xm1 = 0.f, xp4 = 0.f, cbv = 0.f;

    auto loadA = [&](const int k0) {
        if (A_MK) {
            av = *(const float4*)(A + (size_t)(m0 + lrow) * lda + k0 + kq);
        } else {
            const float* row = A + (size_t)(k0 + kk) * lda + m0 + cc;
            av = *(const float4*)row;
            if (CONV) {
                const int t = (m0 + cc) % L_SEQ;   // tok group base within sequence
                xm2 = (t > 0) ? row[-2] : 0.f;     // t==0: left pad (2 zeros)
                xm1 = (t > 0) ? row[-1] : 0.f;
                xp4 = (t < L_SEQ - 4) ? row[4] : 0.f;  // t==140: right pad (1 zero)
                cw4 = *(const float4*)(cw + (k0 + kk) * 4);
                cbv = cb[k0 + kk];
            }
        }
        if (!GN || (n0 + lrow) < N)
            bv = *(const float4*)(Bm + (size_t)(n0 + lrow) * ldb + k0 + kq);
    };

    auto storeLDS = [&]() {
        if (A_MK) {
            As[kq + 0][lrow] = av.x; As[kq + 1][lrow] = av.y;
            As[kq + 2][lrow] = av.z; As[kq + 3][lrow] = av.w;
        } else if (CONV) {
            const float in7[7] = {xm2, xm1, av.x, av.y, av.z, av.w, xp4};
            float4 o;
            float* op = &o.x;
#pragma unroll
            for (int j = 0; j < 4; ++j) {
                float s = cbv;
                s = fmaf(cw4.x, in7[j + 0], s);
                s = fmaf(cw4.y, in7[j + 1], s);
                s = fmaf(cw4.z, in7[j + 2], s);
                s = fmaf(cw4.w, in7[j + 3], s);
                op[j] = s * __builtin_amdgcn_rcpf(1.f + __expf(-s));
            }
            *(float4*)&As[kk][cc] = o;
        } else {
            *(float4*)&As[kk][cc] = av;
        }
        Bs[kq + 0][lrow] = bv.x; Bs[kq + 1][lrow] = bv.y;
        Bs[kq + 2][lrow] = bv.z; Bs[kq + 3][lrow] = bv.w;
    };

    bv = make_float4(0.f, 0.f, 0.f, 0.f);
    loadA(kbeg);
    for (int k0 = kbeg; k0 < kend; k0 += BK) {
        __syncthreads();
        storeLDS();
        __syncthreads();
        if (k0 + BK < kend) loadA(k0 + BK);   // prefetch: regs only, no LDS hazard
#pragma unroll
        for (int k = 0; k < BK; ++k) {
            const float4 a4 = *(const float4*)&As[k][ty * 4];
            const float4 b4 = *(const float4*)&Bs[k][tx * 4];
            const float a_[4] = {a4.x, a4.y, a4.z, a4.w};
            const float b_[4] = {b4.x, b4.y, b4.z, b4.w};
#pragma unroll
            for (int i = 0; i < 4; ++i)
#pragma unroll
                for (int j = 0; j < 4; ++j)
                    acc[i][j] = fmaf(a_[i], b_[j], acc[i][j]);
        }
    }
    C += (size_t)blockIdx.z * sstride;
#pragma unroll
    for (int i = 0; i < 4; ++i) {
        const int gm = m0 + ty * 4 + i;
        const int gn = n0 + tx * 4;
        if (!GN || gn < N)
            *(float4*)(C + (size_t)gm * ldc + gn) =
                make_float4(acc[i][0], acc[i][1], acc[i][2], acc[i][3]);
    }
}

// ---------------------------------------------------------------------------
// gemm3: out[tok][e] = sum_d gT[d][tok] * W_out[e][d]
// Single-pass K=512 (no split-K, no reduce). M=1152, N=256.
// BM=64 x BN3=16 -> 18x16 = 288 blocks; BK=64 -> 16 barriers total.
// Inner step: scalar A broadcast (4-lane shared) x float4 B (16-lane shared)
// => LDS BW trivial; FMA-bound at 2048 FMA/thread.
// ---------------------------------------------------------------------------
__global__ __launch_bounds__(256) void gemm3_k(const float* __restrict__ A,
                                               const float* __restrict__ Bw,
                                               float* __restrict__ C) {
    __shared__ float As[64][BM + 4];    // [k][m]
    __shared__ float Bs[64][BN3 + 4];   // [k][n]
    const int tid = threadIdx.x;
    const int m0 = blockIdx.y * BM;
    const int n0 = blockIdx.x * BN3;
    const int kk = tid >> 4, cc = (tid & 15) * 4;   // A loader: k rows kk+16j, m cols cc..+4
    const int bn = tid >> 4, bk = (tid & 15) * 4;   // B loader: n row bn, k quad bk..+4
    const int r = tid >> 2, c4 = (tid & 3) * 4;     // compute: out row r, col quad c4
    float4 acc = make_float4(0.f, 0.f, 0.f, 0.f);
    float4 av[4], bv;

    auto load = [&](const int k0) {
#pragma unroll
        for (int j = 0; j < 4; ++j)
            av[j] = *(const float4*)(A + (size_t)(k0 + kk + 16 * j) * NTOK + m0 + cc);
        bv = *(const float4*)(Bw + (size_t)(n0 + bn) * D_INNER + k0 + bk);
    };

    load(0);
    for (int k0 = 0; k0 < D_INNER; k0 += 64) {
        __syncthreads();
#pragma unroll
        for (int j = 0; j < 4; ++j)
            *(float4*)&As[kk + 16 * j][cc] = av[j];
        Bs[bk + 0][bn] = bv.x; Bs[bk + 1][bn] = bv.y;
        Bs[bk + 2][bn] = bv.z; Bs[bk + 3][bn] = bv.w;
        __syncthreads();
        if (k0 + 64 < D_INNER) load(k0 + 64);   // register prefetch
#pragma unroll
        for (int k = 0; k < 64; ++k) {
            const float a = As[k][r];
            const float4 b4 = *(const float4*)&Bs[k][c4];
            acc.x = fmaf(a, b4.x, acc.x);
            acc.y = fmaf(a, b4.y, acc.y);
            acc.z = fmaf(a, b4.z, acc.z);
            acc.w = fmaf(a, b4.w, acc.w);
        }
    }
    *(float4*)(C + (size_t)(m0 + r) * D_MODEL + n0 + c4) = acc;
}

// ---------------------------------------------------------------------------
// Fused aux+scan, now also performing the split-K=4 slab reduction inline
// (reads sl3 slabs directly; left-associated sums == old reduce4_k bitwise).
// One wave per (b,d); lane = state n.
// ---------------------------------------------------------------------------
template<int CNT>
__device__ __forceinline__ void scan_chunk(const float* __restrict__ sl3,
                                           const float* __restrict__ xzT,
                                           float* __restrict__ gT,
                                           float4* __restrict__ aux_w,
                                           float (*__restrict__ Pw)[65],
                                           const int d, const int base, const int t0,
                                           const float An2, const float4 wdt,
                                           const float bdt, const float dpv,
                                           const float4 cw4, const float cbv,
                                           const int lane, float& h) {
    if (lane < CNT) {
        const int t = t0 + lane;
        const int tok = base + t;
        // conv(4)+SiLU recompute (bitwise-identical to pre-fusion conv kernel)
        const float* row = xzT + (size_t)d * NTOK + tok;
        float s0 = cbv;
        if (t >= 2) s0 = fmaf(cw4.x, row[-2], s0);
        if (t >= 1) s0 = fmaf(cw4.y, row[-1], s0);
        s0 = fmaf(cw4.z, row[0], s0);
        if (t < L_SEQ - 1) s0 = fmaf(cw4.w, row[1], s0);
        const float ixv = s0 * __builtin_amdgcn_rcpf(1.f + __expf(-s0));

        // dt vector: sum of 4 split-K slabs (left-assoc == reduce4_k)
        const float* q = sl3 + (size_t)tok * NDBC;
        const float4 q0 = *(const float4*)(q);
        const float4 q1 = *(const float4*)(q + SLAB);
        const float4 q2 = *(const float4*)(q + 2 * SLAB);
        const float4 q3 = *(const float4*)(q + 3 * SLAB);
        const float dtx = q0.x + q1.x + q2.x + q3.x;
        const float dty = q0.y + q1.y + q2.y + q3.y;
        const float dtz = q0.z + q1.z + q2.z + q3.z;
        const float dtw = q0.w + q1.w + q2.w + q3.w;
        float s = fmaf(dtx, wdt.x, bdt);
        s = fmaf(dty, wdt.y, s);
        s = fmaf(dtz, wdt.z, s);
        s = fmaf(dtw, wdt.w, s);
        const float delta = fmaxf(s, 0.f) + __logf(1.f + __expf(-fabsf(s)));
        const float zv = xzT[(size_t)(D_INNER + d) * NTOK + tok];
        const float sz = zv * __builtin_amdgcn_rcpf(1.f + __expf(-zv));
        aux_w[lane] = make_float4(delta, delta * ixv, dpv * ixv, sz);
    }
#pragma unroll 8
    for (int i = 0; i < CNT; ++i) {
        const float* p = sl3 + (size_t)(base + t0 + i) * NDBC + DT_RANK + lane;
        const float Bv = p[0] + p[SLAB] + p[2 * SLAB] + p[3 * SLAB];          // coalesced, L2-hot
        const float Cv = p[D_STATE] + p[SLAB + D_STATE] + p[2 * SLAB + D_STATE]
                       + p[3 * SLAB + D_STATE];
        const float4 a4 = aux_w[i];                                // LDS broadcast
        const float dA = __builtin_amdgcn_exp2f(a4.x * An2);       // exp(delta*A)
        h = fmaf(dA, h, a4.y * Bv);
        Pw[i][lane] = h * Cv;
    }
    const int tl = lane & 31, hf = lane >> 5;
    float s2 = 0.f;
    if (tl < CNT) {
#pragma unroll
        for (int j = 0; j < 32; ++j) s2 += Pw[tl][hf * 32 + j];    // 2-way banks: free
    }
    s2 += __shfl_xor(s2, 32, 64);
    if (hf == 0 && tl < CNT) {
        const float4 a4 = aux_w[tl];
        gT[(size_t)d * NTOK + base + t0 + tl] = (s2 + a4.z) * a4.w;  // coalesced
    }
}

__global__ __launch_bounds__(256) void scan_k(const float* __restrict__ sl3,
                                              const float* __restrict__ xzT,
                                              const float* __restrict__ W_dt,
                                              const float* __restrict__ b_dt,
                                              const float* __restrict__ A_log,
                                              const float* __restrict__ Dp,
                                              const float* __restrict__ conv_w,
                                              const float* __restrict__ conv_b,
                                              float* __restrict__ gT) {
    __shared__ float4 aux_s[4][32];
    __shared__ float P[4][32][65];
    const int w = threadIdx.x >> 6, lane = threadIdx.x & 63;
    const int b = blockIdx.x >> 7, dg = blockIdx.x & 127;
    const int d = (dg << 2) | w;
    const int base = b * L_SEQ;
    const float An2 = -__expf(A_log[(d << 6) + lane]) * 1.44269504088896f;
    const float4 wdt = *(const float4*)(W_dt + (d << 2));
    const float bdt = b_dt[d], dpv = Dp[d];
    const float4 cw4 = *(const float4*)(conv_w + (d << 2));
    const float cbv = conv_b[d];
    float h = 0.f;
    scan_chunk<32>(sl3, xzT, gT, aux_s[w], P[w], d, base, 0,   An2, wdt, bdt, dpv, cw4, cbv, lane, h);
    scan_chunk<32>(sl3, xzT, gT, aux_s[w], P[w], d, base, 32,  An2, wdt, bdt, dpv, cw4, cbv, lane, h);
    scan_chunk<32>(sl3, xzT, gT, aux_s[w], P[w], d, base, 64,  An2, wdt, bdt, dpv, cw4, cbv, lane, h);
    scan_chunk<32>(sl3, xzT, gT, aux_s[w], P[w], d, base, 96,  An2, wdt, bdt, dpv, cw4, cbv, lane, h);
    scan_chunk<16>(sl3, xzT, gT, aux_s[w], P[w], d, base, 128, An2, wdt, bdt, dpv, cw4, cbv, lane, h);
}

// ---------------------------------------------------------------------------
extern "C" void kernel_launch(void* const* d_in, const int* in_sizes, int n_in,
                              void* d_out, int out_size, void* d_ws, size_t ws_size,
                              hipStream_t stream) {
    const float* x      = (const float*)d_in[0];
    // d_in[1] = lastin (unused: reference starts from h0 = 0)
    const float* W_in   = (const float*)d_in[2];
    const float* conv_w = (const float*)d_in[3];
    const float* conv_b = (const float*)d_in[4];
    const float* W_x    = (const float*)d_in[5];
    const float* W_dt   = (const float*)d_in[6];
    const float* b_dt   = (const float*)d_in[7];
    const float* A_log  = (const float*)d_in[8];
    const float* Dp     = (const float*)d_in[9];
    const float* W_out  = (const float*)d_in[10];
    float* out = (float*)d_out;

    float* ws  = (float*)d_ws;
    float* xzT = ws;                    // [1024][1152] = 1,179,648 f
    float* sl3 = xzT + 1179648;         // 4 x [1152][132] = 608,256 f
    float* gT  = sl3 + 4 * SLAB;        // [512][1152]  =   589,824 f

    // 1) xzT[e][tok] = W_in[e][:] · x[tok][:]   (M=1024, N=1152, K=256)
    gemm_k<true, false, false><<<dim3(18, 16, 1), 256, 0, stream>>>(
        W_in, x, xzT, NTOK, D_MODEL, D_MODEL, NTOK, nullptr, nullptr, D_MODEL, 0);
    // 2) sl3[z][tok][e] = silu(conv(xz))[tok][:] · W_x[e][:]  (conv fused in A-load)
    //    M=1152, N=132, K=512, split-K=4 slabs (reduced inside scan)
    gemm_k<false, true, true><<<dim3(3, 18, 4), 256, 0, stream>>>(
        xzT, W_x, sl3, NDBC, NTOK, D_INNER, NDBC, conv_w, conv_b, 128,
        (size_t)SLAB);
    // 3) fused slab-reduce + conv + aux + selective scan -> gT[d][tok]
    scan_k<<<dim3(B_SZ * 128), 256, 0, stream>>>(sl3, xzT, W_dt, b_dt, A_log, Dp,
                                                 conv_w, conv_b, gT);
    // 4) out[tok][e] = g[tok][:] · W_out[e][:]  (M=1152, N=256, K=512) single-pass
    gemm3_k<<<dim3(16, 18), 256, 0, stream>>>(gT, W_out, out);
}

// Round 4
// 141.570 us; speedup vs baseline: 1.2428x; 1.2428x over previous
//
#include <hip/hip_runtime.h>

#define B_SZ 8
#define L_SEQ 144
#define NTOK 1152
#define D_MODEL 256
#define D_INNER 512
#define D_STATE 64
#define DT_RANK 4
#define NDBC 132
#define SLAB 152064   // NTOK*NDBC, one split-K slab of dBC

#define BM 64
#define BN 64
#define BK 16

// ---------------------------------------------------------------------------
// Tiled GEMM with register prefetch of the next k-slab.
//  A_MK=true : A stored [m][k] (row stride lda) | false: A stored [k][m]
//  B always stored [n][k] (row stride ldb)
//  GN        : guard n<N on B-loads and C-stores (N=132 case)
//  CONV      : (A_MK=false only) A rows are pre-conv xzT[d][tok]; apply
//              depthwise conv(4)+SiLU on the fly while staging to LDS.
//  PERM      : B-row permutation for the dBC producer so that output cols are
//              [dt(4) | B0 C0 B1 C1 ... B63 C63]  (B/C interleaved).
//              Pure relabeling of output columns -> bitwise-identical values.
// Split-K: blockIdx.z selects k-slab; C advanced by z*sstride.
// ---------------------------------------------------------------------------
__device__ __forceinline__ int bc_perm(const int p) {
    // stored position p -> original W_x row
    return (p < DT_RANK) ? p
         : (((p - DT_RANK) & 1) ? (DT_RANK + D_STATE + ((p - DT_RANK) >> 1))
                                : (DT_RANK + ((p - DT_RANK) >> 1)));
}

template<bool A_MK, bool GN, bool CONV, bool PERM>
__global__ __launch_bounds__(256) void gemm_k(const float* __restrict__ A,
                                              const float* __restrict__ Bm,
                                              float* __restrict__ C,
                                              const int N, const int lda, const int ldb,
                                              const int ldc,
                                              const float* __restrict__ cw,
                                              const float* __restrict__ cb,
                                              const int kslab, const size_t sstride) {
    __shared__ float As[BK][BM + 4];
    __shared__ float Bs[BK][BN + 4];
    const int tid = threadIdx.x;
    const int m0 = blockIdx.y * BM;
    const int n0 = blockIdx.x * BN;
    const int kbeg = blockIdx.z * kslab;
    const int kend = kbeg + kslab;
    const int ty = tid >> 4, tx = tid & 15;
    const int lrow = tid >> 2, kq = (tid & 3) * 4;   // transpose-load indices
    const int kk = tid >> 4, cc = (tid & 15) * 4;    // direct-load indices
    const int brow = PERM ? bc_perm(n0 + lrow) : (n0 + lrow);
    float acc[4][4] = {};
    float4 av, bv, cw4;
    float xm2 = 0.f, xm1 = 0.f, xp4 = 0.f, cbv = 0.f;

    auto loadA = [&](const int k0) {
        if (A_MK) {
            av = *(const float4*)(A + (size_t)(m0 + lrow) * lda + k0 + kq);
        } else {
            const float* row = A + (size_t)(k0 + kk) * lda + m0 + cc;
            av = *(const float4*)row;
            if (CONV) {
                const int t = (m0 + cc) % L_SEQ;   // tok group base within sequence
                xm2 = (t > 0) ? row[-2] : 0.f;     // t==0: left pad (2 zeros)
                xm1 = (t > 0) ? row[-1] : 0.f;
                xp4 = (t < L_SEQ - 4) ? row[4] : 0.f;  // t==140: right pad (1 zero)
                cw4 = *(const float4*)(cw + (k0 + kk) * 4);
                cbv = cb[k0 + kk];
            }
        }
        if (!GN || (n0 + lrow) < N)
            bv = *(const float4*)(Bm + (size_t)brow * ldb + k0 + kq);
    };

    auto storeLDS = [&]() {
        if (A_MK) {
            As[kq + 0][lrow] = av.x; As[kq + 1][lrow] = av.y;
            As[kq + 2][lrow] = av.z; As[kq + 3][lrow] = av.w;
        } else if (CONV) {
            const float in7[7] = {xm2, xm1, av.x, av.y, av.z, av.w, xp4};
            float4 o;
            float* op = &o.x;
#pragma unroll
            for (int j = 0; j < 4; ++j) {
                float s = cbv;
                s = fmaf(cw4.x, in7[j + 0], s);
                s = fmaf(cw4.y, in7[j + 1], s);
                s = fmaf(cw4.z, in7[j + 2], s);
                s = fmaf(cw4.w, in7[j + 3], s);
                op[j] = s * __builtin_amdgcn_rcpf(1.f + __expf(-s));
            }
            *(float4*)&As[kk][cc] = o;
        } else {
            *(float4*)&As[kk][cc] = av;
        }
        Bs[kq + 0][lrow] = bv.x; Bs[kq + 1][lrow] = bv.y;
        Bs[kq + 2][lrow] = bv.z; Bs[kq + 3][lrow] = bv.w;
    };

    bv = make_float4(0.f, 0.f, 0.f, 0.f);
    loadA(kbeg);
    for (int k0 = kbeg; k0 < kend; k0 += BK) {
        __syncthreads();
        storeLDS();
        __syncthreads();
        if (k0 + BK < kend) loadA(k0 + BK);   // prefetch: regs only, no LDS hazard
#pragma unroll
        for (int k = 0; k < BK; ++k) {
            const float4 a4 = *(const float4*)&As[k][ty * 4];
            const float4 b4 = *(const float4*)&Bs[k][tx * 4];
            const float a_[4] = {a4.x, a4.y, a4.z, a4.w};
            const float b_[4] = {b4.x, b4.y, b4.z, b4.w};
#pragma unroll
            for (int i = 0; i < 4; ++i)
#pragma unroll
                for (int j = 0; j < 4; ++j)
                    acc[i][j] = fmaf(a_[i], b_[j], acc[i][j]);
        }
    }
    C += (size_t)blockIdx.z * sstride;
#pragma unroll
    for (int i = 0; i < 4; ++i) {
        const int gm = m0 + ty * 4 + i;
        const int gn = n0 + tx * 4;
        if (!GN || gn < N)
            *(float4*)(C + (size_t)gm * ldc + gn) =
                make_float4(acc[i][0], acc[i][1], acc[i][2], acc[i][3]);
    }
}

// ---------------------------------------------------------------------------
// Split-K slab reduction: out[i] = sum_{s<4} in[i + s*s4], float4-wide
// ---------------------------------------------------------------------------
__global__ __launch_bounds__(256) void reduce4_k(const float4* __restrict__ in,
                                                 float4* __restrict__ out,
                                                 const int n4, const int s4) {
    const int i = blockIdx.x * 256 + threadIdx.x;
    if (i >= n4) return;
    const float4 a = in[i], b = in[i + s4], c = in[i + 2 * s4], d = in[i + 3 * s4];
    out[i] = make_float4(a.x + b.x + c.x + d.x, a.y + b.y + c.y + d.y,
                         a.z + b.z + c.z + d.z, a.w + b.w + c.w + d.w);
}

// ---------------------------------------------------------------------------
// Fused aux+scan. One wave per (b,d); lane = state n. Per 32-token chunk:
//   pre-pass (lane t < CNT): conv+SiLU recompute, delta=softplus(dt·Wdt+b),
//     results kept in the owning lane's REGISTERS (no aux LDS).
//   serial : per token i, one dwordx2 load of interleaved (B,C); delta and
//     delta*ix broadcast from lane i via v_readlane (VALU, not LDS pipe).
//     h = exp2(delta*An2)*h + (delta*ix)*B;  P[i][lane] = h*C
//   reduce : transposed LDS row-sum (half-row per lane + shfl_xor 32)
// No __syncthreads: each wave owns its own P LDS slice.
// ---------------------------------------------------------------------------
__device__ __forceinline__ float bcast(const float v, const int i) {
    return __int_as_float(__builtin_amdgcn_readlane(__float_as_int(v), i));
}

template<int CNT>
__device__ __forceinline__ void scan_chunk(const float* __restrict__ dBC,
                                           const float* __restrict__ xzT,
                                           float* __restrict__ gT,
                                           float (*__restrict__ Pw)[65],
                                           const int d, const int base, const int t0,
                                           const float An2, const float4 wdt,
                                           const float bdt, const float dpv,
                                           const float4 cw4, const float cbv,
                                           const int lane, float& h) {
    float delta_r = 0.f, dix_r = 0.f, dpix_r = 0.f, sz_r = 0.f;
    if (lane < CNT) {
        const int t = t0 + lane;
        const int tok = base + t;
        // conv(4)+SiLU recompute (bitwise-identical to pre-fusion conv kernel)
        const float* row = xzT + (size_t)d * NTOK + tok;
        float s0 = cbv;
        if (t >= 2) s0 = fmaf(cw4.x, row[-2], s0);
        if (t >= 1) s0 = fmaf(cw4.y, row[-1], s0);
        s0 = fmaf(cw4.z, row[0], s0);
        if (t < L_SEQ - 1) s0 = fmaf(cw4.w, row[1], s0);
        const float ixv = s0 * __builtin_amdgcn_rcpf(1.f + __expf(-s0));

        const float4 dt4 = *(const float4*)(dBC + (size_t)tok * NDBC);
        float s = fmaf(dt4.x, wdt.x, bdt);
        s = fmaf(dt4.y, wdt.y, s);
        s = fmaf(dt4.z, wdt.z, s);
        s = fmaf(dt4.w, wdt.w, s);
        const float delta = fmaxf(s, 0.f) + __logf(1.f + __expf(-fabsf(s)));
        const float zv = xzT[(size_t)(D_INNER + d) * NTOK + tok];
        delta_r = delta;
        dix_r   = delta * ixv;
        dpix_r  = dpv * ixv;
        sz_r    = zv * __builtin_amdgcn_rcpf(1.f + __expf(-zv));
    }
#pragma unroll
    for (int i = 0; i < CNT; ++i) {
        // interleaved (B,C) pair for state n=lane: one 8B coalesced load, L2-hot
        const float2 bc = *(const float2*)(dBC + (size_t)(base + t0 + i) * NDBC
                                           + DT_RANK + 2 * lane);
        const float dlt = bcast(delta_r, i);
        const float dxv = bcast(dix_r, i);
        const float dA = __builtin_amdgcn_exp2f(dlt * An2);        // exp(delta*A)
        h = fmaf(dA, h, dxv * bc.x);
        Pw[i][lane] = h * bc.y;
    }
    const int tl = lane & 31, hf = lane >> 5;
    float s2 = 0.f;
    if (tl < CNT) {
#pragma unroll
        for (int j = 0; j < 32; ++j) s2 += Pw[tl][hf * 32 + j];    // 2-way banks: free
    }
    s2 += __shfl_xor(s2, 32, 64);
    if (hf == 0 && tl < CNT) {
        // lane == tl owns token tl's epilogue registers
        gT[(size_t)d * NTOK + base + t0 + tl] = (s2 + dpix_r) * sz_r;  // coalesced
    }
}

__global__ __launch_bounds__(256) void scan_k(const float* __restrict__ dBC,
                                              const float* __restrict__ xzT,
                                              const float* __restrict__ W_dt,
                                              const float* __restrict__ b_dt,
                                              const float* __restrict__ A_log,
                                              const float* __restrict__ Dp,
                                              const float* __restrict__ conv_w,
                                              const float* __restrict__ conv_b,
                                              float* __restrict__ gT) {
    __shared__ float P[4][32][65];
    const int w = threadIdx.x >> 6, lane = threadIdx.x & 63;
    const int b = blockIdx.x >> 7, dg = blockIdx.x & 127;
    const int d = (dg << 2) | w;
    const int base = b * L_SEQ;
    const float An2 = -__expf(A_log[(d << 6) + lane]) * 1.44269504088896f;
    const float4 wdt = *(const float4*)(W_dt + (d << 2));
    const float bdt = b_dt[d], dpv = Dp[d];
    const float4 cw4 = *(const float4*)(conv_w + (d << 2));
    const float cbv = conv_b[d];
    float h = 0.f;
    scan_chunk<32>(dBC, xzT, gT, P[w], d, base, 0,   An2, wdt, bdt, dpv, cw4, cbv, lane, h);
    scan_chunk<32>(dBC, xzT, gT, P[w], d, base, 32,  An2, wdt, bdt, dpv, cw4, cbv, lane, h);
    scan_chunk<32>(dBC, xzT, gT, P[w], d, base, 64,  An2, wdt, bdt, dpv, cw4, cbv, lane, h);
    scan_chunk<32>(dBC, xzT, gT, P[w], d, base, 96,  An2, wdt, bdt, dpv, cw4, cbv, lane, h);
    scan_chunk<16>(dBC, xzT, gT, P[w], d, base, 128, An2, wdt, bdt, dpv, cw4, cbv, lane, h);
}

// ---------------------------------------------------------------------------
extern "C" void kernel_launch(void* const* d_in, const int* in_sizes, int n_in,
                              void* d_out, int out_size, void* d_ws, size_t ws_size,
                              hipStream_t stream) {
    const float* x      = (const float*)d_in[0];
    // d_in[1] = lastin (unused: reference starts from h0 = 0)
    const float* W_in   = (const float*)d_in[2];
    const float* conv_w = (const float*)d_in[3];
    const float* conv_b = (const float*)d_in[4];
    const float* W_x    = (const float*)d_in[5];
    const float* W_dt   = (const float*)d_in[6];
    const float* b_dt   = (const float*)d_in[7];
    const float* A_log  = (const float*)d_in[8];
    const float* Dp     = (const float*)d_in[9];
    const float* W_out  = (const float*)d_in[10];
    float* out = (float*)d_out;

    float* ws  = (float*)d_ws;
    float* xzT = ws;                    // [1024][1152] = 1,179,648 f
    float* dBC = xzT + 1179648;         // [1152][132]  =   152,064 f (interleaved B/C)
    float* gT  = dBC + 152064;          // [512][1152]  =   589,824 f
    float* sl3 = gT + 589824;           // 4×152,064    =   608,256 f
    float* sl6 = xzT;                   // reuse: xzT dead after scan (4×294,912 fits)

    // 1) xzT[e][tok] = W_in[e][:] · x[tok][:]   (M=1024, N=1152, K=256)
    gemm_k<true, false, false, false><<<dim3(18, 16, 1), 256, 0, stream>>>(
        W_in, x, xzT, NTOK, D_MODEL, D_MODEL, NTOK, nullptr, nullptr, D_MODEL, 0);
    // 2) sl3[z][tok][p] = silu(conv(xz))[tok][:] · W_x[perm(p)][:]
    //    (conv fused in A-load; B/C columns interleaved)  M=1152, N=132, K=512, split-K=4
    gemm_k<false, true, true, true><<<dim3(3, 18, 4), 256, 0, stream>>>(
        xzT, W_x, sl3, NDBC, NTOK, D_INNER, NDBC, conv_w, conv_b, 128, (size_t)SLAB);
    reduce4_k<<<dim3(149), 256, 0, stream>>>((const float4*)sl3, (float4*)dBC,
                                             NTOK * NDBC / 4, NTOK * NDBC / 4);
    // 3) fused conv + aux + selective scan -> gT[d][tok]
    scan_k<<<dim3(B_SZ * 128), 256, 0, stream>>>(dBC, xzT, W_dt, b_dt, A_log, Dp,
                                                 conv_w, conv_b, gT);
    // 4) out[tok][e] = g[tok][:] · W_out[e][:]  (M=1152, N=256, K=512) split-K=4
    gemm_k<false, false, false, false><<<dim3(4, 18, 4), 256, 0, stream>>>(
        gT, W_out, sl6, D_MODEL, NTOK, D_INNER, D_MODEL, nullptr, nullptr, 128,
        (size_t)NTOK * D_MODEL);
    reduce4_k<<<dim3(288), 256, 0, stream>>>((const float4*)sl6, (float4*)out,
                                             NTOK * D_MODEL / 4, NTOK * D_MODEL / 4);
}